// Round 7
// baseline (131.908 us; speedup 1.0000x reference)
//
#include <hip/hip_runtime.h>
#include <hip/hip_bf16.h>
#include <cstdint>
#include <cstddef>

// ---------- types ----------
typedef __bf16 bf16x8 __attribute__((ext_vector_type(8)));
typedef float f32x4 __attribute__((ext_vector_type(4)));

__device__ __forceinline__ void gload_lds16(const void* g, void* l) {
  __builtin_amdgcn_global_load_lds((const __attribute__((address_space(1))) void*)g,
                                   (__attribute__((address_space(3))) void*)l, 16, 0, 0);
}
__device__ __forceinline__ unsigned short f2bf(float x) {
  return __builtin_bit_cast(unsigned short, __float2bfloat16(x));
}
#define S_BARRIER asm volatile("s_barrier" ::: "memory")
#define WAIT_VM(N) asm volatile("s_waitcnt vmcnt(" #N ")" ::: "memory")

// ---------- kernel 1: sqrtFc[t][b][c] = sqrt(sum_m |X[b][c][m]|) ----------
__global__ void fc_kernel(const float* __restrict__ TF, const float* __restrict__ SF,
                          float* __restrict__ sqrtFc) {
  int wv = threadIdx.x >> 6, lane = threadIdx.x & 63;
  int row = blockIdx.x * 4 + wv;                 // [0, 16384)
  const float* X = (row < 8192) ? TF : SF;
  const float* p = X + (size_t)(row & 8191) * 1024;
  float s = 0.f;
#pragma unroll
  for (int it = 0; it < 4; ++it) {
    float4 v = *reinterpret_cast<const float4*>(p + (size_t)(it * 64 + lane) * 4);
    s += fabsf(v.x) + fabsf(v.y) + fabsf(v.z) + fabsf(v.w);
  }
#pragma unroll
  for (int m = 32; m; m >>= 1) s += __shfl_xor(s, m);
  if (lane == 0) sqrtFc[row] = sqrtf(s);
}

// ---------- kernel 2: W[b][m][c] = bf16(X[b][c][m] * sqrtFc[b][c]), 64x64 tiles ----------
__global__ void __launch_bounds__(256) wprep2_kernel(const float* __restrict__ TF,
                                                     const float* __restrict__ SF,
                                                     const float* __restrict__ sqrtFc,
                                                     __hip_bfloat16* __restrict__ Wt,
                                                     __hip_bfloat16* __restrict__ Ws) {
  __shared__ float lds[64][65];
  __shared__ float scale[64];
  int z = blockIdx.z;                // t*16 + b
  int t = z >> 4, b = z & 15;
  int m0 = blockIdx.x * 64, c0 = blockIdx.y * 64;
  const float* Xg = (t ? SF : TF) + (size_t)b * 524288;
  __hip_bfloat16* Wg = (t ? Ws : Wt) + (size_t)b * 524288;
  int tid = threadIdx.x;
  if (tid < 64) scale[tid] = sqrtFc[t * 8192 + b * 512 + c0 + tid];
  // read 64 c-rows x 64 m (256B contiguous runs)
#pragma unroll
  for (int i = 0; i < 4; ++i) {
    int v = i * 256 + tid;
    int r = v >> 4, q = v & 15;
    *reinterpret_cast<float4*>(&lds[r][q * 4]) =
        *reinterpret_cast<const float4*>(Xg + (size_t)(c0 + r) * 1024 + m0 + q * 4);
  }
  __syncthreads();
  // write 64 m-rows x 64 c (128B contiguous runs of bf16)
#pragma unroll
  for (int jj = 0; jj < 2; ++jj) {
    int m = jj * 32 + (tid >> 3), oct = tid & 7;
    union { unsigned short h[8]; uint4 u; } pk;
#pragma unroll
    for (int k = 0; k < 8; ++k) {
      int c = oct * 8 + k;
      pk.h[k] = f2bf(lds[c][m] * scale[c]);
    }
    *reinterpret_cast<uint4*>(Wg + (size_t)(m0 + m) * 512 + c0 + oct * 8) = pk.u;
  }
}

// ---------- kernel 3: fused SYRK, counted-vmcnt pipeline ----------
// 576 jobs = 16 batches x 36 upper-tri pairs. 512 thr = 8 waves (4x2), per-wave 32x64.
// BK=64 double-buffered; prefetch stays in flight across barriers (vmcnt(4), never 0).
__global__ void __launch_bounds__(512, 4) syrk_fused_kernel(
    const __hip_bfloat16* __restrict__ Wt, const __hip_bfloat16* __restrict__ Ws,
    float* __restrict__ nT, float* __restrict__ nS, float* __restrict__ cross) {
  __shared__ __hip_bfloat16 AL[2][128 * 64];    // 32 KB
  __shared__ __hip_bfloat16 BL[2][128 * 64];    // 32 KB
  int bid = blockIdx.x;                       // 576 = 8 XCD * 72
  int j = (bid & 7) * 72 + (bid >> 3);        // bijective XCD swizzle: 2 batches/XCD
  int b = j / 36, pair = j % 36;
  int bx = pair, tm = 0;
  while (bx >= 8 - tm) { bx -= 8 - tm; ++tm; }
  int tn = tm + bx;
  bool diag = (tm == tn);
  const __hip_bfloat16* WTb = Wt + (size_t)b * 524288;
  const __hip_bfloat16* WSb = Ws + (size_t)b * 524288;
  const __hip_bfloat16* ATp = WTb + (size_t)tm * 65536;
  const __hip_bfloat16* ASp = WSb + (size_t)tm * 65536;
  const __hip_bfloat16* BTp = WTb + (size_t)tn * 65536;
  const __hip_bfloat16* BSp = WSb + (size_t)tn * 65536;

  const int tid = threadIdx.x;
  const int lane = tid & 63, wv = tid >> 6;
  const int wr = wv >> 1, wc = wv & 1;       // 4x2 wave grid
  const int g = lane >> 4, c0 = lane & 15, cx = c0 & 7;

  // staging: 1024 16B-chunks per 128x64 tile; 2 per thread; swizzled global source
  int offs[2], dst[2];
#pragma unroll
  for (int i = 0; i < 2; ++i) {
    int ci = i * 512 + tid;
    int row = ci >> 3, slot = ci & 7;
    offs[i] = row * 512 + (slot ^ (row & 7)) * 8;
    dst[i] = (i * 512 + wv * 64) * 8;        // wave-uniform base; HW adds lane*16B
  }

  f32x4 accT[2][4], accS[2][4];
#pragma unroll
  for (int mi = 0; mi < 2; ++mi)
#pragma unroll
    for (int ni = 0; ni < 4; ++ni) {
      accT[mi][ni] = (f32x4){0.f, 0.f, 0.f, 0.f};
      accS[mi][ni] = (f32x4){0.f, 0.f, 0.f, 0.f};
    }

  auto stage = [&](int s, int buf) {
    int kt = (s & 7) * 64;
    const __hip_bfloat16* Ab = (s < 8) ? ATp : ASp;
    const __hip_bfloat16* Bb = (s < 8) ? BTp : BSp;
#pragma unroll
    for (int i = 0; i < 2; ++i) {
      gload_lds16(Ab + offs[i] + kt, &AL[buf][dst[i]]);
      gload_lds16(Bb + offs[i] + kt, &BL[buf][dst[i]]);
    }
  };

  stage(0, 0);
#pragma unroll
  for (int s = 0; s < 16; ++s) {             // 0-7: T, 8-15: S
    int buf = s & 1;
    if (s < 15) {
      stage(s + 1, buf ^ 1);
      WAIT_VM(4);                            // wait stage(s); stage(s+1) stays in flight
    } else {
      WAIT_VM(0);
    }
    S_BARRIER;
    const __hip_bfloat16* Ab = AL[buf];
    const __hip_bfloat16* Bb = BL[buf];
#pragma unroll
    for (int kk = 0; kk < 2; ++kk) {
      int ck = ((kk * 4 + g) ^ cx) * 8;
      bf16x8 av[2], bv[4];
#pragma unroll
      for (int mi = 0; mi < 2; ++mi)
        av[mi] = *reinterpret_cast<const bf16x8*>(Ab + (wr * 32 + mi * 16 + c0) * 64 + ck);
#pragma unroll
      for (int ni = 0; ni < 4; ++ni)
        bv[ni] = *reinterpret_cast<const bf16x8*>(Bb + (wc * 64 + ni * 16 + c0) * 64 + ck);
      if (s < 8) {
#pragma unroll
        for (int mi = 0; mi < 2; ++mi)
#pragma unroll
          for (int ni = 0; ni < 4; ++ni)
            accT[mi][ni] = __builtin_amdgcn_mfma_f32_16x16x32_bf16(av[mi], bv[ni], accT[mi][ni], 0, 0, 0);
      } else {
#pragma unroll
        for (int mi = 0; mi < 2; ++mi)
#pragma unroll
          for (int ni = 0; ni < 4; ++ni)
            accS[mi][ni] = __builtin_amdgcn_mfma_f32_16x16x32_bf16(av[mi], bv[ni], accS[mi][ni], 0, 0, 0);
      }
    }
    if (s < 15) S_BARRIER;                   // all reads of buf done before overwrite
  }

  float* pT = nT + (size_t)b * 1024;
  float* pS = nS + (size_t)b * 1024;
  float* pC = cross + (size_t)b * 1024;
  // row-direction sums (over this tile's 128 columns)
#pragma unroll
  for (int mi = 0; mi < 2; ++mi)
#pragma unroll
    for (int r = 0; r < 4; ++r) {
      float sT = 0.f, sS = 0.f, sC = 0.f;
#pragma unroll
      for (int ni = 0; ni < 4; ++ni) {
        float tv = accT[mi][ni][r], sv = accS[mi][ni][r];
        sT += tv * tv; sS += sv * sv; sC += tv * sv;
      }
#pragma unroll
      for (int msk = 1; msk < 16; msk <<= 1) {
        sT += __shfl_xor(sT, msk); sS += __shfl_xor(sS, msk); sC += __shfl_xor(sC, msk);
      }
      if (c0 == 0) {
        int m = tm * 128 + wr * 32 + mi * 16 + g * 4 + r;
        atomicAdd(pT + m, sT); atomicAdd(pS + m, sS); atomicAdd(pC + m, sC);
      }
    }
  // column-direction (transpose) sums, off-diagonal tiles only
  if (!diag) {
#pragma unroll
    for (int ni = 0; ni < 4; ++ni) {
      float sT = 0.f, sS = 0.f, sC = 0.f;
#pragma unroll
      for (int mi = 0; mi < 2; ++mi)
#pragma unroll
        for (int r = 0; r < 4; ++r) {
          float tv = accT[mi][ni][r], sv = accS[mi][ni][r];
          sT += tv * tv; sS += sv * sv; sC += tv * sv;
        }
      sT += __shfl_xor(sT, 16); sS += __shfl_xor(sS, 16); sC += __shfl_xor(sC, 16);
      sT += __shfl_xor(sT, 32); sS += __shfl_xor(sS, 32); sC += __shfl_xor(sC, 32);
      if (g == 0) {
        int n = tn * 128 + wc * 64 + ni * 16 + c0;
        atomicAdd(pT + n, sT); atomicAdd(pS + n, sS); atomicAdd(pC + n, sC);
      }
    }
  }
}

// ---------- kernel 4: channel grams, wave-per-super-pair, conflict-free ----------
__global__ void __launch_bounds__(256) icgram3_kernel(const float* __restrict__ t_out,
                                                      const float* __restrict__ s_out,
                                                      float* __restrict__ G,
                                                      float* __restrict__ outcpy) {
  __shared__ float lds[21 * 516];
  int chunk = blockIdx.x;   // 32 chunks of 512 m
  int z = blockIdx.y;       // t*16 + b
  int t = z >> 4, bb = z & 15;
  const float* L = (t ? s_out : t_out) + (size_t)bb * 344064 + (size_t)chunk * 512;
  float* O = outcpy + (size_t)bb * 344064 + (size_t)chunk * 512;
  int tid = threadIdx.x;    // 256 threads
  for (int idx = tid; idx < 21 * 128; idx += 256) {
    int r = idx >> 7, c = idx & 127;
    float4 v = *reinterpret_cast<const float4*>(L + (size_t)r * 16384 + c * 4);
    if (t) *reinterpret_cast<float4*>(O + (size_t)r * 16384 + c * 4) = v;
    *reinterpret_cast<float4*>(&lds[r * 516 + c * 4]) = v;
  }
  __syncthreads();
  int wv = tid >> 6, lane = tid & 63;
  float* Gz = G + (size_t)z * 441;
  for (int sp = wv; sp < 66; sp += 4) {      // 66 super-pairs over 11x11 upper triangle
    int pp = sp, gi = 0;
    while (pp >= 11 - gi) { pp -= 11 - gi; ++gi; }
    int gj = gi + pp;
    int i0 = 2 * gi, j0 = 2 * gj;
    bool i1v = (i0 + 1 < 21), j1v = (j0 + 1 < 21);
    const float4* Ri0 = reinterpret_cast<const float4*>(&lds[i0 * 516]);
    const float4* Ri1 = reinterpret_cast<const float4*>(&lds[(i1v ? i0 + 1 : i0) * 516]);
    const float4* Rj0 = reinterpret_cast<const float4*>(&lds[j0 * 516]);
    const float4* Rj1 = reinterpret_cast<const float4*>(&lds[(j1v ? j0 + 1 : j0) * 516]);
    // lane-contiguous float4 reads: conflict-free
    float4 a00 = Ri0[lane], a01 = Ri0[lane + 64];
    float4 a10 = Ri1[lane], a11 = Ri1[lane + 64];
    float4 b00 = Rj0[lane], b01 = Rj0[lane + 64];
    float4 b10 = Rj1[lane], b11 = Rj1[lane + 64];
    float s00 = a00.x * b00.x + a00.y * b00.y + a00.z * b00.z + a00.w * b00.w
              + a01.x * b01.x + a01.y * b01.y + a01.z * b01.z + a01.w * b01.w;
    float s01 = a00.x * b10.x + a00.y * b10.y + a00.z * b10.z + a00.w * b10.w
              + a01.x * b11.x + a01.y * b11.y + a01.z * b11.z + a01.w * b11.w;
    float s10 = a10.x * b00.x + a10.y * b00.y + a10.z * b00.z + a10.w * b00.w
              + a11.x * b01.x + a11.y * b01.y + a11.z * b01.z + a11.w * b01.w;
    float s11 = a10.x * b10.x + a10.y * b10.y + a10.z * b10.z + a10.w * b10.w
              + a11.x * b11.x + a11.y * b11.y + a11.z * b11.z + a11.w * b11.w;
    // split reduction: xor1,2 per sum; select by lane&3; xor4..32
    s00 += __shfl_xor(s00, 1); s00 += __shfl_xor(s00, 2);
    s01 += __shfl_xor(s01, 1); s01 += __shfl_xor(s01, 2);
    s10 += __shfl_xor(s10, 1); s10 += __shfl_xor(s10, 2);
    s11 += __shfl_xor(s11, 1); s11 += __shfl_xor(s11, 2);
    int q = lane & 3;
    float sq = (q == 0) ? s00 : (q == 1) ? s01 : (q == 2) ? s10 : s11;
    sq += __shfl_xor(sq, 4); sq += __shfl_xor(sq, 8);
    sq += __shfl_xor(sq, 16); sq += __shfl_xor(sq, 32);
    if (lane < 4) {
      bool ok = (lane == 0) || (lane == 1 && j1v) ||
                (lane == 2 && i1v && gi != gj) || (lane == 3 && i1v && j1v);
      int ii = (lane >> 1) ? i0 + 1 : i0;
      int jj = (lane & 1) ? j0 + 1 : j0;
      if (ok) atomicAdd(&Gz[ii * 21 + jj], sq);
    }
  }
}

// ---------- kernel 5: finalize both losses ----------
__global__ void finalize_kernel(const float* __restrict__ G, const float* __restrict__ nT,
                                const float* __restrict__ nS, const float* __restrict__ cross,
                                float* __restrict__ out2) {
  __shared__ float red[16];
  int tid = threadIdx.x;   // 1024
  float sa = 0.f;
#pragma unroll
  for (int it = 0; it < 4; ++it) {
    int i4 = it * 1024 + tid;
    float4 a = reinterpret_cast<const float4*>(nT)[i4];
    float4 s4 = reinterpret_cast<const float4*>(nS)[i4];
    float4 c4 = reinterpret_cast<const float4*>(cross)[i4];
#pragma unroll
    for (int k = 0; k < 4; ++k) {
      float a1 = (&a.x)[k], s1 = (&s4.x)[k], c1 = (&c4.x)[k];
      float NT = fmaxf(sqrtf(a1), 1e-12f), NS = fmaxf(sqrtf(s1), 1e-12f);
      sa += a1 / (NT * NT) + s1 / (NS * NS) - 2.f * c1 / (NT * NS);
    }
  }
  float ic = 0.f;
  if (tid < 336) {
    int b = tid / 21, i = tid % 21;
    const float* gt = G + (size_t)b * 441;
    const float* gs = G + (size_t)(16 + b) * 441;
    float nt = 0.f, ns = 0.f;
    for (int j = 0; j < 21; ++j) {
      int idx2 = (i <= j) ? i * 21 + j : j * 21 + i;
      float vt = gt[idx2], vs = gs[idx2];
      nt += vt * vt; ns += vs * vs;
    }
    float rt = 1.f / fmaxf(sqrtf(nt), 1e-12f);
    float rs = 1.f / fmaxf(sqrtf(ns), 1e-12f);
    for (int j = 0; j < 21; ++j) {
      int idx2 = (i <= j) ? i * 21 + j : j * 21 + i;
      float d = gs[idx2] * rs - gt[idx2] * rt;
      ic += d * d;
    }
  }
  int lane = tid & 63, wv = tid >> 6;
#pragma unroll
  for (int m = 32; m; m >>= 1) { sa += __shfl_xor(sa, m); ic += __shfl_xor(ic, m); }
  if (lane == 0) red[wv] = sa;
  __syncthreads();
  if (tid == 0) { float s = 0.f; for (int w = 0; w < 16; ++w) s += red[w]; out2[1] = s * (1.0f / 16777216.0f); }
  __syncthreads();
  if (lane == 0) red[wv] = ic;
  __syncthreads();
  if (tid == 0) { float s = 0.f; for (int w = 0; w < 16; ++w) s += red[w]; out2[0] = s * (1.0f / 336.0f); }
}

// ---------- launch ----------
extern "C" void kernel_launch(void* const* d_in, const int* in_sizes, int n_in,
                              void* d_out, int out_size, void* d_ws, size_t ws_size,
                              hipStream_t stream) {
  const float* TF = (const float*)d_in[0];
  const float* SF = (const float*)d_in[1];
  const float* t_out = (const float*)d_in[2];
  const float* s_out = (const float*)d_in[3];
  float* out = (float*)d_out;
  char* ws = (char*)d_ws;

  // ws layout (bytes):
  //   0        : nT    [16][1024] f32  (65536)
  //   65536    : nS    [16][1024] f32  (65536)
  //   131072   : cross [16][1024] f32  (65536)
  //   196608   : G     [32][441]  f32  (56448, zeroed through 253056)
  //   253184   : sqrtFc [16384]   f32  (65536)
  //   318720   : Wt bf16 [16][1024][512] (16777216)
  //   17095936 : Ws bf16 [16][1024][512] (16777216)  -> total ~33.9 MB
  float* nT = (float*)(ws + 0);
  float* nS = (float*)(ws + 65536);
  float* cross = (float*)(ws + 131072);
  float* G = (float*)(ws + 196608);
  float* sqrtFc = (float*)(ws + 253184);
  __hip_bfloat16* Wt = (__hip_bfloat16*)(ws + 318720);
  __hip_bfloat16* Ws = (__hip_bfloat16*)(ws + 318720 + 16777216);

  (void)hipMemsetAsync(ws, 0, 253056, stream);   // nT, nS, cross, G

  fc_kernel<<<4096, 256, 0, stream>>>(TF, SF, sqrtFc);
  wprep2_kernel<<<dim3(16, 8, 32), 256, 0, stream>>>(TF, SF, sqrtFc, Wt, Ws);
  syrk_fused_kernel<<<576, 512, 0, stream>>>(Wt, Ws, nT, nS, cross);
  icgram3_kernel<<<dim3(32, 32), 256, 0, stream>>>(t_out, s_out, G, out);
  finalize_kernel<<<1, 1024, 0, stream>>>(G, nT, nS, cross, out + 5505024);
}

// Round 8
// 126.162 us; speedup vs baseline: 1.0455x; 1.0455x over previous
//
#include <hip/hip_runtime.h>
#include <hip/hip_bf16.h>
#include <cstdint>
#include <cstddef>

// ---------- types ----------
typedef __bf16 bf16x8 __attribute__((ext_vector_type(8)));
typedef float f32x4 __attribute__((ext_vector_type(4)));

__device__ __forceinline__ void gload_lds16(const void* g, void* l) {
  __builtin_amdgcn_global_load_lds((const __attribute__((address_space(1))) void*)g,
                                   (__attribute__((address_space(3))) void*)l, 16, 0, 0);
}
__device__ __forceinline__ unsigned short f2bf(float x) {
  return __builtin_bit_cast(unsigned short, __float2bfloat16(x));
}
#define S_BARRIER asm volatile("s_barrier" ::: "memory")
#define WAIT_VM(N) asm volatile("s_waitcnt vmcnt(" #N ")" ::: "memory")

// ---------- kernel 1: sqrtFc[t][b][c] = sqrt(sum_m |X[b][c][m]|) ----------
__global__ void fc_kernel(const float* __restrict__ TF, const float* __restrict__ SF,
                          float* __restrict__ sqrtFc) {
  int wv = threadIdx.x >> 6, lane = threadIdx.x & 63;
  int row = blockIdx.x * 4 + wv;                 // [0, 16384)
  const float* X = (row < 8192) ? TF : SF;
  const float* p = X + (size_t)(row & 8191) * 1024;
  float s = 0.f;
#pragma unroll
  for (int it = 0; it < 4; ++it) {
    float4 v = *reinterpret_cast<const float4*>(p + (size_t)(it * 64 + lane) * 4);
    s += fabsf(v.x) + fabsf(v.y) + fabsf(v.z) + fabsf(v.w);
  }
#pragma unroll
  for (int m = 32; m; m >>= 1) s += __shfl_xor(s, m);
  if (lane == 0) sqrtFc[row] = sqrtf(s);
}

// ---------- kernel 2: W[b][m][c] = bf16(X[b][c][m] * sqrtFc[b][c]), 64x64 tiles ----------
__global__ void __launch_bounds__(256) wprep2_kernel(const float* __restrict__ TF,
                                                     const float* __restrict__ SF,
                                                     const float* __restrict__ sqrtFc,
                                                     __hip_bfloat16* __restrict__ Wt,
                                                     __hip_bfloat16* __restrict__ Ws) {
  __shared__ float lds[64][65];
  __shared__ float scale[64];
  int z = blockIdx.z;                // t*16 + b
  int t = z >> 4, b = z & 15;
  int m0 = blockIdx.x * 64, c0 = blockIdx.y * 64;
  const float* Xg = (t ? SF : TF) + (size_t)b * 524288;
  __hip_bfloat16* Wg = (t ? Ws : Wt) + (size_t)b * 524288;
  int tid = threadIdx.x;
  if (tid < 64) scale[tid] = sqrtFc[t * 8192 + b * 512 + c0 + tid];
  // read 64 c-rows x 64 m (256B contiguous runs)
#pragma unroll
  for (int i = 0; i < 4; ++i) {
    int v = i * 256 + tid;
    int r = v >> 4, q = v & 15;
    *reinterpret_cast<float4*>(&lds[r][q * 4]) =
        *reinterpret_cast<const float4*>(Xg + (size_t)(c0 + r) * 1024 + m0 + q * 4);
  }
  __syncthreads();
  // write 64 m-rows x 64 c (128B contiguous runs of bf16)
#pragma unroll
  for (int jj = 0; jj < 2; ++jj) {
    int m = jj * 32 + (tid >> 3), oct = tid & 7;
    union { unsigned short h[8]; uint4 u; } pk;
#pragma unroll
    for (int k = 0; k < 8; ++k) {
      int c = oct * 8 + k;
      pk.h[k] = f2bf(lds[c][m] * scale[c]);
    }
    *reinterpret_cast<uint4*>(Wg + (size_t)(m0 + m) * 512 + c0 + oct * 8) = pk.u;
  }
}

// ---------- kernel 3: fused SYRK, counted-vmcnt pipeline (unchanged from r6) ----------
__global__ void __launch_bounds__(512, 4) syrk_fused_kernel(
    const __hip_bfloat16* __restrict__ Wt, const __hip_bfloat16* __restrict__ Ws,
    float* __restrict__ nT, float* __restrict__ nS, float* __restrict__ cross) {
  __shared__ __hip_bfloat16 AL[2][128 * 64];    // 32 KB
  __shared__ __hip_bfloat16 BL[2][128 * 64];    // 32 KB
  int bid = blockIdx.x;                       // 576 = 8 XCD * 72
  int j = (bid & 7) * 72 + (bid >> 3);        // bijective XCD swizzle: 2 batches/XCD
  int b = j / 36, pair = j % 36;
  int bx = pair, tm = 0;
  while (bx >= 8 - tm) { bx -= 8 - tm; ++tm; }
  int tn = tm + bx;
  bool diag = (tm == tn);
  const __hip_bfloat16* WTb = Wt + (size_t)b * 524288;
  const __hip_bfloat16* WSb = Ws + (size_t)b * 524288;
  const __hip_bfloat16* ATp = WTb + (size_t)tm * 65536;
  const __hip_bfloat16* ASp = WSb + (size_t)tm * 65536;
  const __hip_bfloat16* BTp = WTb + (size_t)tn * 65536;
  const __hip_bfloat16* BSp = WSb + (size_t)tn * 65536;

  const int tid = threadIdx.x;
  const int lane = tid & 63, wv = tid >> 6;
  const int wr = wv >> 1, wc = wv & 1;       // 4x2 wave grid
  const int g = lane >> 4, c0 = lane & 15, cx = c0 & 7;

  int offs[2], dst[2];
#pragma unroll
  for (int i = 0; i < 2; ++i) {
    int ci = i * 512 + tid;
    int row = ci >> 3, slot = ci & 7;
    offs[i] = row * 512 + (slot ^ (row & 7)) * 8;
    dst[i] = (i * 512 + wv * 64) * 8;        // wave-uniform base; HW adds lane*16B
  }

  f32x4 accT[2][4], accS[2][4];
#pragma unroll
  for (int mi = 0; mi < 2; ++mi)
#pragma unroll
    for (int ni = 0; ni < 4; ++ni) {
      accT[mi][ni] = (f32x4){0.f, 0.f, 0.f, 0.f};
      accS[mi][ni] = (f32x4){0.f, 0.f, 0.f, 0.f};
    }

  auto stage = [&](int s, int buf) {
    int kt = (s & 7) * 64;
    const __hip_bfloat16* Ab = (s < 8) ? ATp : ASp;
    const __hip_bfloat16* Bb = (s < 8) ? BTp : BSp;
#pragma unroll
    for (int i = 0; i < 2; ++i) {
      gload_lds16(Ab + offs[i] + kt, &AL[buf][dst[i]]);
      gload_lds16(Bb + offs[i] + kt, &BL[buf][dst[i]]);
    }
  };

  stage(0, 0);
#pragma unroll
  for (int s = 0; s < 16; ++s) {             // 0-7: T, 8-15: S
    int buf = s & 1;
    if (s < 15) {
      stage(s + 1, buf ^ 1);
      WAIT_VM(4);                            // wait stage(s); stage(s+1) stays in flight
    } else {
      WAIT_VM(0);
    }
    S_BARRIER;
    const __hip_bfloat16* Ab = AL[buf];
    const __hip_bfloat16* Bb = BL[buf];
#pragma unroll
    for (int kk = 0; kk < 2; ++kk) {
      int ck = ((kk * 4 + g) ^ cx) * 8;
      bf16x8 av[2], bv[4];
#pragma unroll
      for (int mi = 0; mi < 2; ++mi)
        av[mi] = *reinterpret_cast<const bf16x8*>(Ab + (wr * 32 + mi * 16 + c0) * 64 + ck);
#pragma unroll
      for (int ni = 0; ni < 4; ++ni)
        bv[ni] = *reinterpret_cast<const bf16x8*>(Bb + (wc * 64 + ni * 16 + c0) * 64 + ck);
      if (s < 8) {
#pragma unroll
        for (int mi = 0; mi < 2; ++mi)
#pragma unroll
          for (int ni = 0; ni < 4; ++ni)
            accT[mi][ni] = __builtin_amdgcn_mfma_f32_16x16x32_bf16(av[mi], bv[ni], accT[mi][ni], 0, 0, 0);
      } else {
#pragma unroll
        for (int mi = 0; mi < 2; ++mi)
#pragma unroll
          for (int ni = 0; ni < 4; ++ni)
            accS[mi][ni] = __builtin_amdgcn_mfma_f32_16x16x32_bf16(av[mi], bv[ni], accS[mi][ni], 0, 0, 0);
      }
    }
    if (s < 15) S_BARRIER;                   // all reads of buf done before overwrite
  }

  float* pT = nT + (size_t)b * 1024;
  float* pS = nS + (size_t)b * 1024;
  float* pC = cross + (size_t)b * 1024;
#pragma unroll
  for (int mi = 0; mi < 2; ++mi)
#pragma unroll
    for (int r = 0; r < 4; ++r) {
      float sT = 0.f, sS = 0.f, sC = 0.f;
#pragma unroll
      for (int ni = 0; ni < 4; ++ni) {
        float tv = accT[mi][ni][r], sv = accS[mi][ni][r];
        sT += tv * tv; sS += sv * sv; sC += tv * sv;
      }
#pragma unroll
      for (int msk = 1; msk < 16; msk <<= 1) {
        sT += __shfl_xor(sT, msk); sS += __shfl_xor(sS, msk); sC += __shfl_xor(sC, msk);
      }
      if (c0 == 0) {
        int m = tm * 128 + wr * 32 + mi * 16 + g * 4 + r;
        atomicAdd(pT + m, sT); atomicAdd(pS + m, sS); atomicAdd(pC + m, sC);
      }
    }
  if (!diag) {
#pragma unroll
    for (int ni = 0; ni < 4; ++ni) {
      float sT = 0.f, sS = 0.f, sC = 0.f;
#pragma unroll
      for (int mi = 0; mi < 2; ++mi)
#pragma unroll
        for (int r = 0; r < 4; ++r) {
          float tv = accT[mi][ni][r], sv = accS[mi][ni][r];
          sT += tv * tv; sS += sv * sv; sC += tv * sv;
        }
      sT += __shfl_xor(sT, 16); sS += __shfl_xor(sS, 16); sC += __shfl_xor(sC, 16);
      sT += __shfl_xor(sT, 32); sS += __shfl_xor(sS, 32); sC += __shfl_xor(sC, 32);
      if (g == 0) {
        int n = tn * 128 + wc * 64 + ni * 16 + c0;
        atomicAdd(pT + n, sT); atomicAdd(pS + n, sS); atomicAdd(pC + n, sC);
      }
    }
  }
}

// ---------- kernel 4: channel grams, 512 thr, 64 chunks, LDS-accumulated G ----------
__global__ void __launch_bounds__(512) icgram4_kernel(const float* __restrict__ t_out,
                                                      const float* __restrict__ s_out,
                                                      float* __restrict__ G) {
  __shared__ float lds[21 * 260];
  __shared__ float Gs[441];
  int chunk = blockIdx.x;   // 64 chunks of 256 m
  int z = blockIdx.y;       // t*16 + b
  int t = z >> 4, bb = z & 15;
  const float* L = (t ? s_out : t_out) + (size_t)bb * 344064 + (size_t)chunk * 256;
  int tid = threadIdx.x;    // 512 threads = 8 waves
  for (int i = tid; i < 441; i += 512) Gs[i] = 0.f;
  // load 21 rows x 64 float4 (1KB per row), coalesced
  for (int idx = tid; idx < 21 * 64; idx += 512) {
    int r = idx >> 6, c = idx & 63;
    *reinterpret_cast<float4*>(&lds[r * 260 + c * 4]) =
        *reinterpret_cast<const float4*>(L + (size_t)r * 16384 + c * 4);
  }
  __syncthreads();
  int wv = tid >> 6, lane = tid & 63;
  for (int sp = wv; sp < 66; sp += 8) {      // 66 super-pairs over 11x11 upper triangle
    int pp = sp, gi = 0;
    while (pp >= 11 - gi) { pp -= 11 - gi; ++gi; }
    int gj = gi + pp;
    int i0 = 2 * gi, j0 = 2 * gj;
    bool i1v = (i0 + 1 < 21), j1v = (j0 + 1 < 21);
    const float4* Ri0 = reinterpret_cast<const float4*>(&lds[i0 * 260]);
    const float4* Ri1 = reinterpret_cast<const float4*>(&lds[(i1v ? i0 + 1 : i0) * 260]);
    const float4* Rj0 = reinterpret_cast<const float4*>(&lds[j0 * 260]);
    const float4* Rj1 = reinterpret_cast<const float4*>(&lds[(j1v ? j0 + 1 : j0) * 260]);
    float4 a0 = Ri0[lane], a1 = Ri1[lane];
    float4 b0 = Rj0[lane], b1 = Rj1[lane];
    float s00 = a0.x * b0.x + a0.y * b0.y + a0.z * b0.z + a0.w * b0.w;
    float s01 = a0.x * b1.x + a0.y * b1.y + a0.z * b1.z + a0.w * b1.w;
    float s10 = a1.x * b0.x + a1.y * b0.y + a1.z * b0.z + a1.w * b0.w;
    float s11 = a1.x * b1.x + a1.y * b1.y + a1.z * b1.z + a1.w * b1.w;
    s00 += __shfl_xor(s00, 1); s00 += __shfl_xor(s00, 2);
    s01 += __shfl_xor(s01, 1); s01 += __shfl_xor(s01, 2);
    s10 += __shfl_xor(s10, 1); s10 += __shfl_xor(s10, 2);
    s11 += __shfl_xor(s11, 1); s11 += __shfl_xor(s11, 2);
    int q = lane & 3;
    float sq = (q == 0) ? s00 : (q == 1) ? s01 : (q == 2) ? s10 : s11;
    sq += __shfl_xor(sq, 4); sq += __shfl_xor(sq, 8);
    sq += __shfl_xor(sq, 16); sq += __shfl_xor(sq, 32);
    if (lane < 4) {
      bool ok = (lane == 0) || (lane == 1 && j1v) ||
                (lane == 2 && i1v && gi != gj) || (lane == 3 && i1v && j1v);
      int ii = (lane >> 1) ? i0 + 1 : i0;
      int jj = (lane & 1) ? j0 + 1 : j0;
      if (ok) atomicAdd(&Gs[ii * 21 + jj], sq);
    }
  }
  __syncthreads();
  float* Gz = G + (size_t)z * 441;
  for (int i = tid; i < 441; i += 512) {
    float v = Gs[i];
    if (v != 0.f) atomicAdd(&Gz[i], v);
  }
}

// ---------- kernel 5: finalize both losses ----------
__global__ void finalize_kernel(const float* __restrict__ G, const float* __restrict__ nT,
                                const float* __restrict__ nS, const float* __restrict__ cross,
                                float* __restrict__ out2) {
  __shared__ float red[16];
  int tid = threadIdx.x;   // 1024
  float sa = 0.f;
#pragma unroll
  for (int it = 0; it < 4; ++it) {
    int i4 = it * 1024 + tid;
    float4 a = reinterpret_cast<const float4*>(nT)[i4];
    float4 s4 = reinterpret_cast<const float4*>(nS)[i4];
    float4 c4 = reinterpret_cast<const float4*>(cross)[i4];
#pragma unroll
    for (int k = 0; k < 4; ++k) {
      float a1 = (&a.x)[k], s1 = (&s4.x)[k], c1 = (&c4.x)[k];
      float NT = fmaxf(sqrtf(a1), 1e-12f), NS = fmaxf(sqrtf(s1), 1e-12f);
      sa += a1 / (NT * NT) + s1 / (NS * NS) - 2.f * c1 / (NT * NS);
    }
  }
  float ic = 0.f;
  if (tid < 336) {
    int b = tid / 21, i = tid % 21;
    const float* gt = G + (size_t)b * 441;
    const float* gs = G + (size_t)(16 + b) * 441;
    float nt = 0.f, ns = 0.f;
    for (int j = 0; j < 21; ++j) {
      int idx2 = (i <= j) ? i * 21 + j : j * 21 + i;
      float vt = gt[idx2], vs = gs[idx2];
      nt += vt * vt; ns += vs * vs;
    }
    float rt = 1.f / fmaxf(sqrtf(nt), 1e-12f);
    float rs = 1.f / fmaxf(sqrtf(ns), 1e-12f);
    for (int j = 0; j < 21; ++j) {
      int idx2 = (i <= j) ? i * 21 + j : j * 21 + i;
      float d = gs[idx2] * rs - gt[idx2] * rt;
      ic += d * d;
    }
  }
  int lane = tid & 63, wv = tid >> 6;
#pragma unroll
  for (int m = 32; m; m >>= 1) { sa += __shfl_xor(sa, m); ic += __shfl_xor(ic, m); }
  if (lane == 0) red[wv] = sa;
  __syncthreads();
  if (tid == 0) { float s = 0.f; for (int w = 0; w < 16; ++w) s += red[w]; out2[1] = s * (1.0f / 16777216.0f); }
  __syncthreads();
  if (lane == 0) red[wv] = ic;
  __syncthreads();
  if (tid == 0) { float s = 0.f; for (int w = 0; w < 16; ++w) s += red[w]; out2[0] = s * (1.0f / 336.0f); }
}

// ---------- launch ----------
extern "C" void kernel_launch(void* const* d_in, const int* in_sizes, int n_in,
                              void* d_out, int out_size, void* d_ws, size_t ws_size,
                              hipStream_t stream) {
  const float* TF = (const float*)d_in[0];
  const float* SF = (const float*)d_in[1];
  const float* t_out = (const float*)d_in[2];
  const float* s_out = (const float*)d_in[3];
  float* out = (float*)d_out;
  char* ws = (char*)d_ws;

  // ws layout (bytes):
  //   0        : nT    [16][1024] f32  (65536)
  //   65536    : nS    [16][1024] f32  (65536)
  //   131072   : cross [16][1024] f32  (65536)
  //   196608   : G     [32][441]  f32  (56448, zeroed through 253056)
  //   253184   : sqrtFc [16384]   f32  (65536)
  //   318720   : Wt bf16 [16][1024][512] (16777216)
  //   17095936 : Ws bf16 [16][1024][512] (16777216)  -> total ~33.9 MB
  float* nT = (float*)(ws + 0);
  float* nS = (float*)(ws + 65536);
  float* cross = (float*)(ws + 131072);
  float* G = (float*)(ws + 196608);
  float* sqrtFc = (float*)(ws + 253184);
  __hip_bfloat16* Wt = (__hip_bfloat16*)(ws + 318720);
  __hip_bfloat16* Ws = (__hip_bfloat16*)(ws + 318720 + 16777216);

  (void)hipMemsetAsync(ws, 0, 253056, stream);   // nT, nS, cross, G
  (void)hipMemcpyAsync(d_out, (const void*)s_out, (size_t)5505024 * 4,
                       hipMemcpyDeviceToDevice, stream);

  fc_kernel<<<4096, 256, 0, stream>>>(TF, SF, sqrtFc);
  wprep2_kernel<<<dim3(16, 8, 32), 256, 0, stream>>>(TF, SF, sqrtFc, Wt, Ws);
  syrk_fused_kernel<<<576, 512, 0, stream>>>(Wt, Ws, nT, nS, cross);
  icgram4_kernel<<<dim3(64, 32), 512, 0, stream>>>(t_out, s_out, G);
  finalize_kernel<<<1, 1024, 0, stream>>>(G, nT, nS, cross, out + 5505024);
}